// Round 22
// baseline (120.108 us; speedup 1.0000x reference)
//
#include <hip/hip_runtime.h>
#include <hip/hip_bf16.h>
#include <math.h>

#define S_LEN 4096
#define DMODEL 768
#define NH 12
#define HD 64

using f32x4 = __attribute__((ext_vector_type(4))) float;
using s16x8 = __attribute__((ext_vector_type(8))) short;

__device__ inline ushort f2bf(float f) {
  union { float f; uint32_t u; } v; v.f = f;
  uint32_t r = v.u + 0x7fffu + ((v.u >> 16) & 1u);   // RTNE
  return (ushort)(r >> 16);
}
__device__ __forceinline__ float fexp2(float x) {   // single v_exp_f32, no OCML
  float r;
  asm("v_exp_f32 %0, %1" : "=v"(r) : "v"(x));
  return r;
}

__device__ __forceinline__ void gload16(const ushort* g, ushort* l) {
  __builtin_amdgcn_global_load_lds(
      (const __attribute__((address_space(1))) unsigned int*)g,
      (__attribute__((address_space(3))) unsigned int*)l, 16, 0, 0);
}

// scale folded into q: 1/sqrt(64) * log2(e)  -> softmax uses exp2.
#define QSCL 0.18033688011112042f
// log2(10000)/32
#define L2_1E4_D32 0.4152410118655622f

// ---------------- fused prep: trig + weight transposes + x cast -------------
__device__ void tsplit_dev(const float* __restrict__ W, ushort* __restrict__ Th,
                           int R, int C, int bx, int by,
                           int t, float (*tile)[33]) {
  const int tx = t & 31, ty = t >> 5;
  const int c0 = bx * 32, r0 = by * 32;
#pragma unroll
  for (int i = 0; i < 4; ++i)
    tile[ty + 8 * i][tx] = W[(size_t)(r0 + ty + 8 * i) * C + c0 + tx];
  __syncthreads();
#pragma unroll
  for (int i = 0; i < 4; ++i) {
    const float v = tile[tx][ty + 8 * i];
    const size_t off = (size_t)(c0 + ty + 8 * i) * R + r0 + tx;
    Th[off] = f2bf(v);
  }
}

__global__ __launch_bounds__(256) void k_prep(
    const float* __restrict__ x, const float* __restrict__ Wqkv,
    const float* __restrict__ Wout, float* __restrict__ ct,
    float* __restrict__ st, ushort* __restrict__ Wth,
    ushort* __restrict__ Woth, ushort* __restrict__ xh) {
  __shared__ float tile[32][33];
  const int b = blockIdx.x, t = threadIdx.x;
  if (b < 1024) {                       // trig: all-f32 (mimics np f32 path)
    const int s = (b << 2) | (t >> 6), d = t & 63, j = d & 31;
    const float invf = fexp2(-L2_1E4_D32 * (float)j);   // 10000^(-j/32)
    const float af = (float)s * invf;
    ct[s * HD + d] = cosf(af);
    st[s * HD + d] = sinf(af);
  } else if (b < 2752) {                // W_qkv^T: R=768, C=2304
    const int bb = b - 1024;
    tsplit_dev(Wqkv, Wth, DMODEL, 3 * DMODEL, bb % 72, bb / 72, t, tile);
  } else if (b < 3328) {                // W_out^T
    const int bb = b - 2752;
    tsplit_dev(Wout, Woth, DMODEL, DMODEL, bb % 24, bb / 24, t, tile);
  } else {                              // x -> plain bf16
    const int i = (b - 3328) * 256 + t;
    const float4 v = ((const float4*)x)[i];
    ushort4 h;
    h.x = f2bf(v.x); h.y = f2bf(v.y); h.z = f2bf(v.z); h.w = f2bf(v.w);
    ((ushort4*)xh)[i] = h;
  }
}

// ---------------- bf16 MFMA GEMM, BMx128 tile, BK=64, dbuf pipeline ---------
// Plain bf16 A and B. XCD-aware bijective block swizzle (grid%8==0).
// stage(kt+1) issued BEFORE compute(kt): HBM latency hides under MFMA.
// V stored with the PV-fragment quad-permutation baked into GLOBAL layout.
template <int EPI, int BM>
__global__ __launch_bounds__(256) void k_gemm_split(
    const ushort* __restrict__ Ah, const ushort* __restrict__ Bh,
    const float* __restrict__ bias,
    const float* __restrict__ ct, const float* __restrict__ st,
    ushort* __restrict__ qh,
    ushort* __restrict__ kh, ushort* __restrict__ vt,
    float* __restrict__ out) {
  constexpr int MF = BM / 32;
  constexpr int SSH = BM * 64 + 8192;            // shorts per buffer
  __shared__ __align__(16) ushort SS[2 * SSH];

  const int t = threadIdx.x;
  const int w = t >> 6, l = t & 63, g = l >> 4, lq = l & 15;
  const int wm = w >> 1, wn = w & 1;
  const int nbx = gridDim.x;
  int lin = blockIdx.y * nbx + blockIdx.x;
  const int cpx = (nbx * gridDim.y) >> 3;
  lin = (lin & 7) * cpx + (lin >> 3);            // bijective (grid%8==0)
  const int m0 = (lin / nbx) * BM, n0 = (lin % nbx) * 128;

  f32x4 acc[MF][4];
#pragma unroll
  for (int i = 0; i < MF; ++i)
#pragma unroll
    for (int j = 0; j < 4; ++j) acc[i][j] = (f32x4){0.f, 0.f, 0.f, 0.f};

  const ushort* gsrc;
  ushort* lbase;
  int ninst;
  if (w == 0)      { gsrc = Ah + (size_t)m0 * 768;            lbase = SS;                ninst = BM / 16; }
  else if (w == 1) { gsrc = Ah + (size_t)(m0 + BM / 2) * 768; lbase = SS + BM * 32;      ninst = BM / 16; }
  else if (w == 2) { gsrc = Bh + (size_t)n0 * 768;            lbase = SS + BM * 64;      ninst = 8; }
  else             { gsrc = Bh + (size_t)(n0 + 64) * 768;     lbase = SS + BM * 64 + 4096; ninst = 8; }
  const int grow = l >> 3, gch = l & 7;
  gsrc += (size_t)grow * 768 + ((gch ^ grow) << 3);

  auto gstage = [&](const int kt, const int B) {
#pragma unroll
    for (int i = 0; i < 16; ++i)
      if (i < ninst)
        gload16(gsrc + (size_t)i * (8 * 768) + kt * 64, lbase + B * SSH + i * 512);
  };

  const ushort* rdA[2], * rdB[2];
#pragma unroll
  for (int kk = 0; kk < 2; ++kk) {
    rdA[kk] = SS + wm * (BM / 2) * 64 + lq * 64 + ((((kk << 2) | g) ^ (lq & 7)) << 3);
    rdB[kk] = SS + BM * 64 + wn * 4096 + lq * 64 + ((((kk << 2) | g) ^ (lq & 7)) << 3);
  }

  auto gbody = [&](const int kt, const int CUR, const int NX, const bool pref) {
    if (pref) gstage(kt + 1, NX);   // issue next tile's DMA; drains at barrier
#pragma unroll
    for (int kk = 0; kk < 2; ++kk) {
      s16x8 ah[MF];
#pragma unroll
      for (int mf = 0; mf < MF; ++mf)
        ah[mf] = *(const s16x8*)(rdA[kk] + CUR * SSH + mf * 1024);
      __builtin_amdgcn_s_setprio(1);
#pragma unroll
      for (int nf = 0; nf < 4; ++nf) {
        const s16x8 bhf = *(const s16x8*)(rdB[kk] + CUR * SSH + nf * 1024);
#pragma unroll
        for (int mf = 0; mf < MF; ++mf)
          acc[mf][nf] = __builtin_amdgcn_mfma_f32_16x16x32_bf16(ah[mf], bhf, acc[mf][nf], 0, 0, 0);
      }
      __builtin_amdgcn_s_setprio(0);
    }
    __syncthreads();   // drains DMA (vmcnt) + all LDS reads of buf CUR
  };

  gstage(0, 0);
  __syncthreads();
  for (int p = 0; p < 6; ++p) {
    gbody(2 * p, 0, 1, true);
    gbody(2 * p + 1, 1, 0, p < 5);
  }

  if constexpr (EPI == 0) {
    const int cidx = n0 / DMODEL;   // 0:q 1:k 2:v (block-uniform)
    if (cidx < 2) {
      ushort* dh = (cidx == 0) ? qh : kh;
      const float scl = (cidx == 0) ? QSCL : 1.0f;
#pragma unroll
      for (int nf = 0; nf < 4; ++nf) {
        const int n = n0 + wn * 64 + nf * 16 + lq;
        const int rem = n - cidx * DMODEL;
        const int hh = rem >> 6, d = rem & 63;
        const float sgn = (d & 1) ? 1.f : -1.f;
        const float bb = bias[n];
#pragma unroll
        for (int mf = 0; mf < MF; ++mf)
#pragma unroll
          for (int rg = 0; rg < 4; ++rg) {
            const int s = m0 + wm * (BM / 2) + mf * 16 + g * 4 + rg;
            const float v = acc[mf][nf][rg] + bb;
            const float vp = __shfl_xor(v, 1, 64);
            const float o = (v * ct[s * HD + d] + sgn * vp * st[s * HD + d]) * scl;
            const size_t off = (((size_t)hh * S_LEN + s) << 6) + d;
            dh[off] = f2bf(o);
          }
      }
    } else {
#pragma unroll
      for (int nf = 0; nf < 4; ++nf) {
        const int n = n0 + wn * 64 + nf * 16 + lq;
        const int rem = n - 2 * DMODEL;
        const int hh = rem >> 6, d = rem & 63;
        const float bb = bias[n];
#pragma unroll
        for (int mf = 0; mf < MF; ++mf) {
          union { ushort us[4]; ushort4 u4; } u;
#pragma unroll
          for (int rg = 0; rg < 4; ++rg) u.us[rg] = f2bf(acc[mf][nf][rg] + bb);
          const int sb = m0 + wm * (BM / 2) + mf * 16 + g * 4;
          // permuted V layout: quad at 16a+4g -> 8g+4a within 32-group
          const int sbp = (sb & ~31) | (g << 3) | ((mf & 1) << 2);
          *(ushort4*)(vt + ((size_t)hh * 64 + d) * S_LEN + sbp) = u.u4;
        }
      }
    }
  } else {
#pragma unroll
    for (int nf = 0; nf < 4; ++nf) {
      const int n = n0 + wn * 64 + nf * 16 + lq;
      const float bb = bias[n];
#pragma unroll
      for (int mf = 0; mf < MF; ++mf)
#pragma unroll
        for (int rg = 0; rg < 4; ++rg) {
          const int s = m0 + wm * (BM / 2) + mf * 16 + g * 4 + rg;
          out[(size_t)s * DMODEL + n] = acc[mf][nf][rg] + bb;
        }
    }
  }
}

// ---------------- flash attention: interleaved exp2 under QK MFMAs ---------
// grid (S/64, H), 256 threads = 4 waves; wave w owns q-rows s0+16w..+15.
// exp(sc[n]) issued right after its 2 MFMAs (no setprio fence around QK):
// trans-pipe latency hides under QK(n+1)'s MFMA issue.
__global__ __launch_bounds__(256) void k_attn_mfma(
    const ushort* __restrict__ qh,
    const ushort* __restrict__ kh, const ushort* __restrict__ vtp,
    ushort* __restrict__ cxh) {
  const int h = blockIdx.y;
  const int s0 = blockIdx.x << 6;
  const int t = threadIdx.x;
  const int w = t >> 6, l = t & 63, lq = l & 15, g = l >> 4;

  __shared__ __align__(16) ushort Ks0[2 * 4096];  // [buf][64 k][64 d] swz img
  __shared__ __align__(16) ushort Vs0[2 * 4096];  // [buf][64 d][64 k-perm] swz

  s16x8 qa0, qa1;
  {
    const size_t qoff = ((size_t)h * S_LEN + s0 + (w << 4) + lq) * 64 + (g << 3);
    qa0 = *(const s16x8*)(qh + qoff);
    qa1 = *(const s16x8*)(qh + qoff + 32);
  }
  s16x8 ones;
#pragma unroll
  for (int i = 0; i < 8; ++i) ones[i] = (short)0x3F80;   // bf16 1.0

  f32x4 o[4];
#pragma unroll
  for (int m = 0; m < 4; ++m) o[m] = (f32x4){0.f, 0.f, 0.f, 0.f};
  f32x4 lacc = {0.f, 0.f, 0.f, 0.f};

  // DMA staging: wave w stages K rows 16w..16w+15 and V rows 16w..16w+15
  const int srow0 = (w << 4) + (l >> 3);
  const int sx = ((l & 7) ^ (l >> 3)) << 3;       // pre-XORed chunk
  const ushort* gk = kh + ((size_t)h * S_LEN + srow0) * 64 + sx;
  const ushort* gv = vtp + (((size_t)h << 6) + srow0) * S_LEN + sx;
  ushort* ldK = Ks0 + srow0 * 64 + ((l & 7) << 3);
  ushort* ldV = Vs0 + srow0 * 64 + ((l & 7) << 3);

  auto stage = [&](const int kt, const int B) {
    const ushort* pk = gk + ((size_t)kt << 12);
    const ushort* pv = gv + (kt << 6);
    gload16(pk, ldK + B * 4096);
    gload16(pk + 512, ldK + B * 4096 + 512);
    gload16(pv, ldV + B * 4096);
    gload16(pv + (size_t)8 * S_LEN, ldV + B * 4096 + 512);
  };

  // loop-invariant read bases
  const int b0 = (lq << 6) | ((g ^ (lq & 7)) << 3);
  const int b1 = (lq << 6) | (((g + 4) ^ (lq & 7)) << 3);
  const ushort* kr0 = Ks0 + b0;
  const ushort* kr1 = Ks0 + b1;
  const ushort* vr0 = Vs0 + b0;
  const ushort* vr1 = Vs0 + b1;

  stage(0, 0);
  __syncthreads();

  auto body = [&](const int kt, const int CUR, const int NX, bool pref) {
    if (pref) stage(kt + 1, NX);   // drains at body-end barrier

    // ---- QK^T swapped with exp2 fused into the n-loop ----
    float pr[4][4];
#pragma unroll
    for (int n = 0; n < 4; ++n) {
      const s16x8 ka0 = *(const s16x8*)(kr0 + CUR * 4096 + (n << 10));
      const s16x8 ka1 = *(const s16x8*)(kr1 + CUR * 4096 + (n << 10));
      f32x4 a = {0.f, 0.f, 0.f, 0.f};
      a = __builtin_amdgcn_mfma_f32_16x16x32_bf16(ka0, qa0, a, 0, 0, 0);
      a = __builtin_amdgcn_mfma_f32_16x16x32_bf16(ka1, qa1, a, 0, 0, 0);
      pr[n][0] = fexp2(a[0]);
      pr[n][1] = fexp2(a[1]);
      pr[n][2] = fexp2(a[2]);
      pr[n][3] = fexp2(a[3]);
    }

    // ---- P -> bf16 B-fragments, in-register ----
    uint32_t u[8];
#pragma unroll
    for (int n = 0; n < 4; ++n) {
      asm("v_cvt_pk_bf16_f32 %0, %1, %2"
          : "=v"(u[2 * n]) : "v"(pr[n][0]), "v"(pr[n][1]));
      asm("v_cvt_pk_bf16_f32 %0, %1, %2"
          : "=v"(u[2 * n + 1]) : "v"(pr[n][2]), "v"(pr[n][3]));
    }
    union { uint32_t uw[4]; s16x8 v; } p0, p1;
    p0.uw[0] = u[0]; p0.uw[1] = u[1]; p0.uw[2] = u[2]; p0.uw[3] = u[3];
    p1.uw[0] = u[4]; p1.uw[1] = u[5]; p1.uw[2] = u[6]; p1.uw[3] = u[7];

    // ---- PV swapped + l via ones-MFMA ----
    __builtin_amdgcn_s_setprio(1);
    lacc = __builtin_amdgcn_mfma_f32_16x16x32_bf16(ones, p0.v, lacc, 0, 0, 0);
    lacc = __builtin_amdgcn_mfma_f32_16x16x32_bf16(ones, p1.v, lacc, 0, 0, 0);
#pragma unroll
    for (int m = 0; m < 4; ++m) {
      const s16x8 va0 = *(const s16x8*)(vr0 + CUR * 4096 + (m << 10));
      const s16x8 va1 = *(const s16x8*)(vr1 + CUR * 4096 + (m << 10));
      o[m] = __builtin_amdgcn_mfma_f32_16x16x32_bf16(va0, p0.v, o[m], 0, 0, 0);
      o[m] = __builtin_amdgcn_mfma_f32_16x16x32_bf16(va1, p1.v, o[m], 0, 0, 0);
    }
    __builtin_amdgcn_s_setprio(0);

    __syncthreads();   // drains DMA (vmcnt) + all LDS reads of buf CUR
  };

  for (int p = 0; p < 32; ++p) {
    body(2 * p, 0, 1, true);             // kt = 2p
    body(2 * p + 1, 1, 0, p < 31);       // kt = 2p+1
  }

  // epilogue: lacc[0] is the complete l for q=lq; normalize, write bf16 ctx
  const float inv = 1.0f / lacc[0];
  const size_t rowoff = (size_t)(s0 + (w << 4) + lq) * DMODEL + (h << 6) + (g << 2);
  ushort* hrow = cxh + rowoff;
#pragma unroll
  for (int m = 0; m < 4; ++m) {
    const float v0 = o[m][0] * inv, v1 = o[m][1] * inv;
    const float v2 = o[m][2] * inv, v3 = o[m][3] * inv;
    uint32_t h01, h23;
    asm("v_cvt_pk_bf16_f32 %0, %1, %2" : "=v"(h01) : "v"(v0), "v"(v1));
    asm("v_cvt_pk_bf16_f32 %0, %1, %2" : "=v"(h23) : "v"(v2), "v"(v3));
    uint2 hq;
    hq.x = h01; hq.y = h23;
    *(uint2*)(hrow + (m << 4)) = hq;
  }
}

extern "C" void kernel_launch(void* const* d_in, const int* in_sizes, int n_in,
                              void* d_out, int out_size, void* d_ws, size_t ws_size,
                              hipStream_t stream) {
  const float* x    = (const float*)d_in[0];
  const float* Wqkv = (const float*)d_in[1];
  const float* bqkv = (const float*)d_in[2];
  const float* Wout = (const float*)d_in[3];
  const float* bout = (const float*)d_in[4];
  float* out = (float*)d_out;

  const size_t NQ = (size_t)NH * S_LEN * HD;   // 3,145,728
  const size_t ND = (size_t)S_LEN * DMODEL;    // 3,145,728
  char* base = (char*)d_ws;
  ushort* qh = (ushort*)base;
  ushort* kh = qh + NQ;
  ushort* vt = kh + NQ;          // permuted V layout [H][64][S-perm]
  ushort* xh = vt + NQ;          // [S][768] bf16; reused as ctx after qkv GEMM
  float* ct = (float*)(xh + ND);
  float* st = ct + (size_t)S_LEN * HD;
  ushort* Wth = (ushort*)(st + (size_t)S_LEN * HD);    // [2304][768] bf16
  ushort* Woth = Wth + (size_t)3 * DMODEL * DMODEL;    // [768][768] bf16

  k_prep<<<dim3(6400), dim3(256), 0, stream>>>(
      x, Wqkv, Wout, ct, st, Wth, Woth, xh);
  k_gemm_split<0, 128><<<dim3(3 * DMODEL / 128, S_LEN / 128), dim3(256), 0, stream>>>(
      xh, Wth, bqkv, ct, st, qh, kh, vt, nullptr);
  k_attn_mfma<<<dim3(S_LEN / 64, NH), dim3(256), 0, stream>>>(
      qh, kh, vt, xh);
  k_gemm_split<1, 64><<<dim3(DMODEL / 128, S_LEN / 64), dim3(256), 0, stream>>>(
      xh, Woth, bout, nullptr, nullptr,
      nullptr, nullptr, nullptr, out);
}

// Round 23
// 117.574 us; speedup vs baseline: 1.0216x; 1.0216x over previous
//
#include <hip/hip_runtime.h>
#include <hip/hip_bf16.h>
#include <math.h>

#define S_LEN 4096
#define DMODEL 768
#define NH 12
#define HD 64

using f32x4 = __attribute__((ext_vector_type(4))) float;
using s16x8 = __attribute__((ext_vector_type(8))) short;

__device__ inline ushort f2bf(float f) {
  union { float f; uint32_t u; } v; v.f = f;
  uint32_t r = v.u + 0x7fffu + ((v.u >> 16) & 1u);   // RTNE
  return (ushort)(r >> 16);
}
__device__ __forceinline__ float fexp2(float x) {   // single v_exp_f32, no OCML
  float r;
  asm("v_exp_f32 %0, %1" : "=v"(r) : "v"(x));
  return r;
}

__device__ __forceinline__ void gload16(const ushort* g, ushort* l) {
  __builtin_amdgcn_global_load_lds(
      (const __attribute__((address_space(1))) unsigned int*)g,
      (__attribute__((address_space(3))) unsigned int*)l, 16, 0, 0);
}

// scale folded into q: 1/sqrt(64) * log2(e)  -> softmax uses exp2.
#define QSCL 0.18033688011112042f
// log2(10000)/32
#define L2_1E4_D32 0.4152410118655622f

// ---------------- fused prep: trig + weight transposes + x cast -------------
__device__ void tsplit_dev(const float* __restrict__ W, ushort* __restrict__ Th,
                           int R, int C, int bx, int by,
                           int t, float (*tile)[33]) {
  const int tx = t & 31, ty = t >> 5;
  const int c0 = bx * 32, r0 = by * 32;
#pragma unroll
  for (int i = 0; i < 4; ++i)
    tile[ty + 8 * i][tx] = W[(size_t)(r0 + ty + 8 * i) * C + c0 + tx];
  __syncthreads();
#pragma unroll
  for (int i = 0; i < 4; ++i) {
    const float v = tile[tx][ty + 8 * i];
    const size_t off = (size_t)(c0 + ty + 8 * i) * R + r0 + tx;
    Th[off] = f2bf(v);
  }
}

__global__ __launch_bounds__(256) void k_prep(
    const float* __restrict__ x, const float* __restrict__ Wqkv,
    const float* __restrict__ Wout, float* __restrict__ ct,
    float* __restrict__ st, ushort* __restrict__ Wth,
    ushort* __restrict__ Woth, ushort* __restrict__ xh) {
  __shared__ float tile[32][33];
  const int b = blockIdx.x, t = threadIdx.x;
  if (b < 1024) {                       // trig: all-f32 (mimics np f32 path)
    const int s = (b << 2) | (t >> 6), d = t & 63, j = d & 31;
    const float invf = fexp2(-L2_1E4_D32 * (float)j);   // 10000^(-j/32)
    const float af = (float)s * invf;
    ct[s * HD + d] = cosf(af);
    st[s * HD + d] = sinf(af);
  } else if (b < 2752) {                // W_qkv^T: R=768, C=2304
    const int bb = b - 1024;
    tsplit_dev(Wqkv, Wth, DMODEL, 3 * DMODEL, bb % 72, bb / 72, t, tile);
  } else if (b < 3328) {                // W_out^T
    const int bb = b - 2752;
    tsplit_dev(Wout, Woth, DMODEL, DMODEL, bb % 24, bb / 24, t, tile);
  } else {                              // x -> plain bf16
    const int i = (b - 3328) * 256 + t;
    const float4 v = ((const float4*)x)[i];
    ushort4 h;
    h.x = f2bf(v.x); h.y = f2bf(v.y); h.z = f2bf(v.z); h.w = f2bf(v.w);
    ((ushort4*)xh)[i] = h;
  }
}

// ---------------- bf16 MFMA GEMM, BMx128 tile, BK=64, dbuf pipeline ---------
// Plain bf16 A and B. XCD-aware bijective block swizzle (grid%8==0).
// stage(kt+1) issued BEFORE compute(kt): HBM latency hides under MFMA.
// V stored with the PV-fragment quad-permutation baked into GLOBAL layout.
template <int EPI, int BM>
__global__ __launch_bounds__(256) void k_gemm_split(
    const ushort* __restrict__ Ah, const ushort* __restrict__ Bh,
    const float* __restrict__ bias,
    const float* __restrict__ ct, const float* __restrict__ st,
    ushort* __restrict__ qh,
    ushort* __restrict__ kh, ushort* __restrict__ vt,
    float* __restrict__ out) {
  constexpr int MF = BM / 32;
  constexpr int SSH = BM * 64 + 8192;            // shorts per buffer
  __shared__ __align__(16) ushort SS[2 * SSH];

  const int t = threadIdx.x;
  const int w = t >> 6, l = t & 63, g = l >> 4, lq = l & 15;
  const int wm = w >> 1, wn = w & 1;
  const int nbx = gridDim.x;
  int lin = blockIdx.y * nbx + blockIdx.x;
  const int cpx = (nbx * gridDim.y) >> 3;
  lin = (lin & 7) * cpx + (lin >> 3);            // bijective (grid%8==0)
  const int m0 = (lin / nbx) * BM, n0 = (lin % nbx) * 128;

  f32x4 acc[MF][4];
#pragma unroll
  for (int i = 0; i < MF; ++i)
#pragma unroll
    for (int j = 0; j < 4; ++j) acc[i][j] = (f32x4){0.f, 0.f, 0.f, 0.f};

  const ushort* gsrc;
  ushort* lbase;
  int ninst;
  if (w == 0)      { gsrc = Ah + (size_t)m0 * 768;            lbase = SS;                ninst = BM / 16; }
  else if (w == 1) { gsrc = Ah + (size_t)(m0 + BM / 2) * 768; lbase = SS + BM * 32;      ninst = BM / 16; }
  else if (w == 2) { gsrc = Bh + (size_t)n0 * 768;            lbase = SS + BM * 64;      ninst = 8; }
  else             { gsrc = Bh + (size_t)(n0 + 64) * 768;     lbase = SS + BM * 64 + 4096; ninst = 8; }
  const int grow = l >> 3, gch = l & 7;
  gsrc += (size_t)grow * 768 + ((gch ^ grow) << 3);

  auto gstage = [&](const int kt, const int B) {
#pragma unroll
    for (int i = 0; i < 16; ++i)
      if (i < ninst)
        gload16(gsrc + (size_t)i * (8 * 768) + kt * 64, lbase + B * SSH + i * 512);
  };

  const ushort* rdA[2], * rdB[2];
#pragma unroll
  for (int kk = 0; kk < 2; ++kk) {
    rdA[kk] = SS + wm * (BM / 2) * 64 + lq * 64 + ((((kk << 2) | g) ^ (lq & 7)) << 3);
    rdB[kk] = SS + BM * 64 + wn * 4096 + lq * 64 + ((((kk << 2) | g) ^ (lq & 7)) << 3);
  }

  auto gbody = [&](const int kt, const int CUR, const int NX, const bool pref) {
    if (pref) gstage(kt + 1, NX);   // issue next tile's DMA; drains at barrier
#pragma unroll
    for (int kk = 0; kk < 2; ++kk) {
      s16x8 ah[MF];
#pragma unroll
      for (int mf = 0; mf < MF; ++mf)
        ah[mf] = *(const s16x8*)(rdA[kk] + CUR * SSH + mf * 1024);
      __builtin_amdgcn_s_setprio(1);
#pragma unroll
      for (int nf = 0; nf < 4; ++nf) {
        const s16x8 bhf = *(const s16x8*)(rdB[kk] + CUR * SSH + nf * 1024);
#pragma unroll
        for (int mf = 0; mf < MF; ++mf)
          acc[mf][nf] = __builtin_amdgcn_mfma_f32_16x16x32_bf16(ah[mf], bhf, acc[mf][nf], 0, 0, 0);
      }
      __builtin_amdgcn_s_setprio(0);
    }
    __syncthreads();   // drains DMA (vmcnt) + all LDS reads of buf CUR
  };

  gstage(0, 0);
  __syncthreads();
  for (int p = 0; p < 6; ++p) {
    gbody(2 * p, 0, 1, true);
    gbody(2 * p + 1, 1, 0, p < 5);
  }

  if constexpr (EPI == 0) {
    const int cidx = n0 / DMODEL;   // 0:q 1:k 2:v (block-uniform)
    if (cidx < 2) {
      ushort* dh = (cidx == 0) ? qh : kh;
      const float scl = (cidx == 0) ? QSCL : 1.0f;
#pragma unroll
      for (int nf = 0; nf < 4; ++nf) {
        const int n = n0 + wn * 64 + nf * 16 + lq;
        const int rem = n - cidx * DMODEL;
        const int hh = rem >> 6, d = rem & 63;
        const float sgn = (d & 1) ? 1.f : -1.f;
        const float bb = bias[n];
#pragma unroll
        for (int mf = 0; mf < MF; ++mf)
#pragma unroll
          for (int rg = 0; rg < 4; ++rg) {
            const int s = m0 + wm * (BM / 2) + mf * 16 + g * 4 + rg;
            const float v = acc[mf][nf][rg] + bb;
            const float vp = __shfl_xor(v, 1, 64);
            const float o = (v * ct[s * HD + d] + sgn * vp * st[s * HD + d]) * scl;
            const size_t off = (((size_t)hh * S_LEN + s) << 6) + d;
            dh[off] = f2bf(o);
          }
      }
    } else {
#pragma unroll
      for (int nf = 0; nf < 4; ++nf) {
        const int n = n0 + wn * 64 + nf * 16 + lq;
        const int rem = n - 2 * DMODEL;
        const int hh = rem >> 6, d = rem & 63;
        const float bb = bias[n];
#pragma unroll
        for (int mf = 0; mf < MF; ++mf) {
          union { ushort us[4]; ushort4 u4; } u;
#pragma unroll
          for (int rg = 0; rg < 4; ++rg) u.us[rg] = f2bf(acc[mf][nf][rg] + bb);
          const int sb = m0 + wm * (BM / 2) + mf * 16 + g * 4;
          // permuted V layout: quad at 16a+4g -> 8g+4a within 32-group
          const int sbp = (sb & ~31) | (g << 3) | ((mf & 1) << 2);
          *(ushort4*)(vt + ((size_t)hh * 64 + d) * S_LEN + sbp) = u.u4;
        }
      }
    }
  } else {
#pragma unroll
    for (int nf = 0; nf < 4; ++nf) {
      const int n = n0 + wn * 64 + nf * 16 + lq;
      const float bb = bias[n];
#pragma unroll
      for (int mf = 0; mf < MF; ++mf)
#pragma unroll
        for (int rg = 0; rg < 4; ++rg) {
          const int s = m0 + wm * (BM / 2) + mf * 16 + g * 4 + rg;
          out[(size_t)s * DMODEL + n] = acc[mf][nf][rg] + bb;
        }
    }
  }
}

// ---------------- flash attention: interleaved exp2 under QK MFMAs ---------
// grid (S/64, H), 256 threads = 4 waves; wave w owns q-rows s0+16w..+15.
__global__ __launch_bounds__(256) void k_attn_mfma(
    const ushort* __restrict__ qh,
    const ushort* __restrict__ kh, const ushort* __restrict__ vtp,
    ushort* __restrict__ cxh) {
  const int h = blockIdx.y;
  const int s0 = blockIdx.x << 6;
  const int t = threadIdx.x;
  const int w = t >> 6, l = t & 63, lq = l & 15, g = l >> 4;

  __shared__ __align__(16) ushort Ks0[2 * 4096];  // [buf][64 k][64 d] swz img
  __shared__ __align__(16) ushort Vs0[2 * 4096];  // [buf][64 d][64 k-perm] swz

  s16x8 qa0, qa1;
  {
    const size_t qoff = ((size_t)h * S_LEN + s0 + (w << 4) + lq) * 64 + (g << 3);
    qa0 = *(const s16x8*)(qh + qoff);
    qa1 = *(const s16x8*)(qh + qoff + 32);
  }
  s16x8 ones;
#pragma unroll
  for (int i = 0; i < 8; ++i) ones[i] = (short)0x3F80;   // bf16 1.0

  f32x4 o[4];
#pragma unroll
  for (int m = 0; m < 4; ++m) o[m] = (f32x4){0.f, 0.f, 0.f, 0.f};
  f32x4 lacc = {0.f, 0.f, 0.f, 0.f};

  // DMA staging: wave w stages K rows 16w..16w+15 and V rows 16w..16w+15
  const int srow0 = (w << 4) + (l >> 3);
  const int sx = ((l & 7) ^ (l >> 3)) << 3;       // pre-XORed chunk
  const ushort* gk = kh + ((size_t)h * S_LEN + srow0) * 64 + sx;
  const ushort* gv = vtp + (((size_t)h << 6) + srow0) * S_LEN + sx;
  ushort* ldK = Ks0 + srow0 * 64 + ((l & 7) << 3);
  ushort* ldV = Vs0 + srow0 * 64 + ((l & 7) << 3);

  auto stage = [&](const int kt, const int B) {
    const ushort* pk = gk + ((size_t)kt << 12);
    const ushort* pv = gv + (kt << 6);
    gload16(pk, ldK + B * 4096);
    gload16(pk + 512, ldK + B * 4096 + 512);
    gload16(pv, ldV + B * 4096);
    gload16(pv + (size_t)8 * S_LEN, ldV + B * 4096 + 512);
  };

  // loop-invariant read bases
  const int b0 = (lq << 6) | ((g ^ (lq & 7)) << 3);
  const int b1 = (lq << 6) | (((g + 4) ^ (lq & 7)) << 3);
  const ushort* kr0 = Ks0 + b0;
  const ushort* kr1 = Ks0 + b1;
  const ushort* vr0 = Vs0 + b0;
  const ushort* vr1 = Vs0 + b1;

  stage(0, 0);
  __syncthreads();

  auto body = [&](const int kt, const int CUR, const int NX, bool pref) {
    if (pref) stage(kt + 1, NX);   // drains at body-end barrier

    // ---- QK^T swapped with exp2 fused into the n-loop ----
    float pr[4][4];
#pragma unroll
    for (int n = 0; n < 4; ++n) {
      const s16x8 ka0 = *(const s16x8*)(kr0 + CUR * 4096 + (n << 10));
      const s16x8 ka1 = *(const s16x8*)(kr1 + CUR * 4096 + (n << 10));
      f32x4 a = {0.f, 0.f, 0.f, 0.f};
      a = __builtin_amdgcn_mfma_f32_16x16x32_bf16(ka0, qa0, a, 0, 0, 0);
      a = __builtin_amdgcn_mfma_f32_16x16x32_bf16(ka1, qa1, a, 0, 0, 0);
      pr[n][0] = fexp2(a[0]);
      pr[n][1] = fexp2(a[1]);
      pr[n][2] = fexp2(a[2]);
      pr[n][3] = fexp2(a[3]);
    }

    // ---- P -> bf16 B-fragments, in-register ----
    uint32_t u[8];
#pragma unroll
    for (int n = 0; n < 4; ++n) {
      asm("v_cvt_pk_bf16_f32 %0, %1, %2"
          : "=v"(u[2 * n]) : "v"(pr[n][0]), "v"(pr[n][1]));
      asm("v_cvt_pk_bf16_f32 %0, %1, %2"
          : "=v"(u[2 * n + 1]) : "v"(pr[n][2]), "v"(pr[n][3]));
    }
    union { uint32_t uw[4]; s16x8 v; } p0, p1;
    p0.uw[0] = u[0]; p0.uw[1] = u[1]; p0.uw[2] = u[2]; p0.uw[3] = u[3];
    p1.uw[0] = u[4]; p1.uw[1] = u[5]; p1.uw[2] = u[6]; p1.uw[3] = u[7];

    // ---- PV swapped + l via ones-MFMA ----
    __builtin_amdgcn_s_setprio(1);
    lacc = __builtin_amdgcn_mfma_f32_16x16x32_bf16(ones, p0.v, lacc, 0, 0, 0);
    lacc = __builtin_amdgcn_mfma_f32_16x16x32_bf16(ones, p1.v, lacc, 0, 0, 0);
#pragma unroll
    for (int m = 0; m < 4; ++m) {
      const s16x8 va0 = *(const s16x8*)(vr0 + CUR * 4096 + (m << 10));
      const s16x8 va1 = *(const s16x8*)(vr1 + CUR * 4096 + (m << 10));
      o[m] = __builtin_amdgcn_mfma_f32_16x16x32_bf16(va0, p0.v, o[m], 0, 0, 0);
      o[m] = __builtin_amdgcn_mfma_f32_16x16x32_bf16(va1, p1.v, o[m], 0, 0, 0);
    }
    __builtin_amdgcn_s_setprio(0);

    __syncthreads();   // drains DMA (vmcnt) + all LDS reads of buf CUR
  };

  for (int p = 0; p < 32; ++p) {
    body(2 * p, 0, 1, true);             // kt = 2p
    body(2 * p + 1, 1, 0, p < 31);       // kt = 2p+1
  }

  // epilogue: lacc[0] is the complete l for q=lq; normalize, write bf16 ctx
  const float inv = 1.0f / lacc[0];
  const size_t rowoff = (size_t)(s0 + (w << 4) + lq) * DMODEL + (h << 6) + (g << 2);
  ushort* hrow = cxh + rowoff;
#pragma unroll
  for (int m = 0; m < 4; ++m) {
    const float v0 = o[m][0] * inv, v1 = o[m][1] * inv;
    const float v2 = o[m][2] * inv, v3 = o[m][3] * inv;
    uint32_t h01, h23;
    asm("v_cvt_pk_bf16_f32 %0, %1, %2" : "=v"(h01) : "v"(v0), "v"(v1));
    asm("v_cvt_pk_bf16_f32 %0, %1, %2" : "=v"(h23) : "v"(v2), "v"(v3));
    uint2 hq;
    hq.x = h01; hq.y = h23;
    *(uint2*)(hrow + (m << 4)) = hq;
  }
}

extern "C" void kernel_launch(void* const* d_in, const int* in_sizes, int n_in,
                              void* d_out, int out_size, void* d_ws, size_t ws_size,
                              hipStream_t stream) {
  const float* x    = (const float*)d_in[0];
  const float* Wqkv = (const float*)d_in[1];
  const float* bqkv = (const float*)d_in[2];
  const float* Wout = (const float*)d_in[3];
  const float* bout = (const float*)d_in[4];
  float* out = (float*)d_out;

  const size_t NQ = (size_t)NH * S_LEN * HD;   // 3,145,728
  const size_t ND = (size_t)S_LEN * DMODEL;    // 3,145,728
  char* base = (char*)d_ws;
  ushort* qh = (ushort*)base;
  ushort* kh = qh + NQ;
  ushort* vt = kh + NQ;          // permuted V layout [H][64][S-perm]
  ushort* xh = vt + NQ;          // [S][768] bf16; reused as ctx after qkv GEMM
  float* ct = (float*)(xh + ND);
  float* st = ct + (size_t)S_LEN * HD;
  ushort* Wth = (ushort*)(st + (size_t)S_LEN * HD);    // [2304][768] bf16
  ushort* Woth = Wth + (size_t)3 * DMODEL * DMODEL;    // [768][768] bf16

  k_prep<<<dim3(6400), dim3(256), 0, stream>>>(
      x, Wqkv, Wout, ct, st, Wth, Woth, xh);
  k_gemm_split<0, 64><<<dim3(3 * DMODEL / 128, S_LEN / 64), dim3(256), 0, stream>>>(
      xh, Wth, bqkv, ct, st, qh, kh, vt, nullptr);
  k_attn_mfma<<<dim3(S_LEN / 64, NH), dim3(256), 0, stream>>>(
      qh, kh, vt, xh);
  k_gemm_split<1, 64><<<dim3(DMODEL / 128, S_LEN / 64), dim3(256), 0, stream>>>(
      xh, Woth, bout, nullptr, nullptr,
      nullptr, nullptr, nullptr, out);
}